// Round 5
// baseline (431.732 us; speedup 1.0000x reference)
//
#include <hip/hip_runtime.h>

// ---------------------------------------------------------------------------
// Elementwise tensor product (e3nn-style), MUL=128, Ls=[0,1,2]
//   in : f1, f2  [16384, 1152] fp32
//   out:         [16384, 4480] fp32
// Round 5: LDS input staging with float4 coalesced loads (kills ~28 scalar
// strided global loads/thread + duplicate l=2 fetch). Work split and LDS
// output staging as round 4.
// ---------------------------------------------------------------------------

#define NROW 16384
#define DIN  1152
#define DOUT 4480

// table layout (floats): (l,lo) -> offset
//  (0,0):0[1] (1,0):1[9] (1,1):10[27] (1,2):37[45]
//  (2,0):82[25] (2,1):107[75] (2,2):182[125] (2,3):307[175] (2,4):482[225]  total 707
__device__ float g_cgtab[707];

struct cd { double x, y; };
__device__ __forceinline__ cd cmul(cd a, cd b) {
    return cd{a.x * b.x - a.y * b.y, a.x * b.y + a.y * b.x};
}

__device__ __forceinline__ int imax(int a, int b) { return a > b ? a : b; }
__device__ __forceinline__ int imin(int a, int b) { return a < b ? a : b; }

// SU(2) Clebsch-Gordan (Racah), fp64
__device__ double su2_cg_d(int j1, int m1, int j2, int m2, int j3, int m3,
                           const double* f) {
    if (m3 != m1 + m2) return 0.0;
    int vmin = imax(imax(-j1 + j2 + m3, -j1 + m1), 0);
    int vmax = imin(imin(j2 + j3 + m1, j3 - j1 + j2), j3 + m3);
    if (vmax < vmin) return 0.0;
    double c = sqrt((2.0 * j3 + 1.0) *
                    f[j3 + j1 - j2] * f[j3 - j1 + j2] * f[j1 + j2 - j3] *
                    f[j3 + m3] * f[j3 - m3] /
                    (f[j1 + j2 + j3 + 1] * f[j1 - m1] * f[j1 + m1] *
                     f[j2 - m2] * f[j2 + m2]));
    double s = 0.0;
    for (int v = vmin; v <= vmax; ++v) {
        double num = f[j2 + j3 + m1 - v] * f[j1 - m1 + v];
        double den = f[v] * f[j3 - j1 + j2 - v] * f[j3 + m3 - v] * f[v + j1 - j2 - m3];
        double term = num / den;
        s += ((v + j2 + m2) & 1) ? -term : term;
    }
    return c * s;
}

// real->complex SH change of basis, e3nn convention incl (-i)^l phase
__device__ void fill_cb(int l, cd* q) {
    int d = 2 * l + 1;
    for (int i = 0; i < d * d; i++) q[i] = cd{0.0, 0.0};
    const double is2 = 0.70710678118654752440;
    for (int m = -l; m < 0; m++) {
        q[(l + m) * d + (l - m)] = cd{is2, 0.0};
        q[(l + m) * d + (l + m)] = cd{0.0, -is2};
    }
    q[l * d + l] = cd{1.0, 0.0};
    for (int m = 1; m <= l; m++) {
        double sg = (m & 1) ? -1.0 : 1.0;
        q[(l + m) * d + (l + m)] = cd{sg * is2, 0.0};
        q[(l + m) * d + (l - m)] = cd{0.0, sg * is2};
    }
    int ph = l & 3;  // multiply by (-i)^l
    for (int i = 0; i < d * d; i++) {
        cd z = q[i], r;
        if (ph == 0) r = z;
        else if (ph == 1) r = cd{z.y, -z.x};
        else if (ph == 2) r = cd{-z.x, -z.y};
        else r = cd{-z.y, z.x};
        q[i] = r;
    }
}

// one block per (l,lo) pair; writes normalized real-basis w3j * sqrt(2lo+1)
__global__ void cg_gen() {
    int b = blockIdx.x;  // 0..8
    int l = (b == 0) ? 0 : (b < 4 ? 1 : 2);
    int lo = (b == 0) ? 0 : (b < 4 ? b - 1 : b - 4);
    int base = (l == 0) ? 0 : (l == 1 ? 1 : 82);
    int d2 = 2 * l + 1, d1 = 2 * lo + 1;
    int off = base + d2 * d2 * lo * lo;
    int Nent = d1 * d2 * d2;

    __shared__ double fct[12];
    __shared__ double su2[225];
    __shared__ cd cb1[81];
    __shared__ cd cb2[25];
    __shared__ double val[225];

    if (threadIdx.x == 0) {
        fct[0] = 1.0;
        for (int i = 1; i < 12; i++) fct[i] = fct[i - 1] * i;
    }
    __syncthreads();

    for (int e = threadIdx.x; e < Nent; e += blockDim.x) {
        int i = e / (d2 * d2), r = e % (d2 * d2);
        int k = r / d2, n = r % d2;
        su2[e] = su2_cg_d(lo, i - lo, l, k - l, l, n - l, fct);
    }
    if (threadIdx.x == 0) { fill_cb(lo, cb1); fill_cb(l, cb2); }
    __syncthreads();

    for (int e = threadIdx.x; e < Nent; e += blockDim.x) {
        int jo = e / (d2 * d2), r = e % (d2 * d2);
        int kb = r / d2, mb = r % d2;
        double sx = 0.0;
        for (int i = 0; i < d1; i++) {
            cd c1 = cb1[i * d1 + jo];
            for (int k = 0; k < d2; k++) {
                cd c12 = cmul(c1, cb2[k * d2 + kb]);
                for (int n = 0; n < d2; n++) {
                    double cv = su2[(i * d2 + k) * d2 + n];
                    if (cv != 0.0) {
                        cd c3 = cb2[n * d2 + mb];
                        c3.y = -c3.y;
                        cd term = cmul(c12, c3);
                        sx += term.x * cv;
                    }
                }
            }
        }
        val[e] = sx;
    }
    __syncthreads();

    double ss = 0.0;
    for (int e = 0; e < Nent; e++) { double v = val[e]; ss += v * v; }
    double scale = sqrt((double)d1) / sqrt(ss);
    for (int e = threadIdx.x; e < Nent; e += blockDim.x)
        g_cgtab[off + e] = (float)(val[e] * scale);
}

// ---------------------------------------------------------------------------
// main kernel. LDS:
//   lin[2304]: f1 row @[0..1152), f2 row @[1152..2304)  (9.2 KB)
//   os[4096] : output stage (16 KB)
//     (1,1)@0[384] (1,2)@384[640] (2,1)@1024[384] (2,2)@1408[640]
//     (2,3)@2048[896] (2,4)@2944[1152]
//   out runs: lds[0..1024) -> out[256..1280); lds[1024..4096) -> out[1408..4480)
// ---------------------------------------------------------------------------

// os[k] = sum_e t[k*NE+e] * q[e]   (q = precomputed a_i*b_j products)
template <int DO_, int NE>
__device__ __forceinline__ void contractP(const float* __restrict__ t,
                                          const float* q,
                                          float* __restrict__ os) {
#pragma unroll
    for (int k = 0; k < DO_; k++) {
        float acc = 0.0f;
#pragma unroll
        for (int e = 0; e < NE; e++) acc = fmaf(t[k * NE + e], q[e], acc);
        os[k] = acc;
    }
}

__global__ __launch_bounds__(256, 6) void etp_main(
    const float* __restrict__ f1, const float* __restrict__ f2,
    float* __restrict__ out) {
    __shared__ alignas(16) float lin[2304];
    __shared__ alignas(16) float os[4096];
    const float* __restrict__ t = g_cgtab;  // uniform -> scalar cache

    const int tid = threadIdx.x;
    const int ch = tid & 127;
    const size_t row = blockIdx.x;

    // ---- coalesced input staging: 288 float4 per operand ----
    {
        const float4* __restrict__ s1 =
            reinterpret_cast<const float4*>(f1 + row * DIN);
        const float4* __restrict__ s2 =
            reinterpret_cast<const float4*>(f2 + row * DIN);
        float4* __restrict__ li = reinterpret_cast<float4*>(lin);
        li[tid] = s1[tid];
        li[288 + tid] = s2[tid];
        if (tid < 32) {
            li[256 + tid] = s1[256 + tid];
            li[544 + tid] = s2[256 + tid];
        }
    }
    __syncthreads();

    const float* __restrict__ L1 = lin;         // f1 row
    const float* __restrict__ L2 = lin + 1152;  // f2 row
    float* __restrict__ po = out + row * DOUT;

    if (tid < 128) {
        // ---- waves 0-1: l=0, l=1 (all), and (2,4) ----
        float a0 = L1[ch], b0 = L2[ch];
        po[ch] = t[0] * a0 * b0;  // (0,0)

        float a1[3], b1[3];
#pragma unroll
        for (int k = 0; k < 3; k++) {
            a1[k] = L1[128 + ch * 3 + k];
            b1[k] = L2[128 + ch * 3 + k];
        }
        float q1[9];
#pragma unroll
        for (int i = 0; i < 3; i++)
#pragma unroll
            for (int j = 0; j < 3; j++) q1[i * 3 + j] = a1[i] * b1[j];
        {
            float s = 0.0f;  // (1,0) direct
#pragma unroll
            for (int e = 0; e < 9; e++) s = fmaf(t[1 + e], q1[e], s);
            po[128 + ch] = s;
        }
        contractP<3, 9>(t + 10, q1, os + 0 + ch * 3);    // (1,1)
        contractP<5, 9>(t + 37, q1, os + 384 + ch * 5);  // (1,2)

        float a2[5], b2[5];
#pragma unroll
        for (int k = 0; k < 5; k++) {
            a2[k] = L1[512 + ch * 5 + k];
            b2[k] = L2[512 + ch * 5 + k];
        }
        float q2[25];
#pragma unroll
        for (int i = 0; i < 5; i++)
#pragma unroll
            for (int j = 0; j < 5; j++) q2[i * 5 + j] = a2[i] * b2[j];
        contractP<9, 25>(t + 482, q2, os + 2944 + ch * 9);  // (2,4)
    } else {
        // ---- waves 2-3: (2,0), (2,1), (2,2), (2,3) ----
        float a2[5], b2[5];
#pragma unroll
        for (int k = 0; k < 5; k++) {
            a2[k] = L1[512 + ch * 5 + k];
            b2[k] = L2[512 + ch * 5 + k];
        }
        float q2[25];
#pragma unroll
        for (int i = 0; i < 5; i++)
#pragma unroll
            for (int j = 0; j < 5; j++) q2[i * 5 + j] = a2[i] * b2[j];
        {
            float s = 0.0f;  // (2,0) direct
#pragma unroll
            for (int e = 0; e < 25; e++) s = fmaf(t[82 + e], q2[e], s);
            po[1280 + ch] = s;
        }
        contractP<3, 25>(t + 107, q2, os + 1024 + ch * 3);  // (2,1)
        contractP<5, 25>(t + 182, q2, os + 1408 + ch * 5);  // (2,2)
        contractP<7, 25>(t + 307, q2, os + 2048 + ch * 7);  // (2,3)
    }

    __syncthreads();

    // ---- coalesced copy-out: 1024 float4 by 256 threads ----
    const float4* __restrict__ src = reinterpret_cast<const float4*>(os);
    float4* __restrict__ dA = reinterpret_cast<float4*>(po + 256);
    float4* __restrict__ dB = reinterpret_cast<float4*>(po + 1408);
    dA[tid] = src[tid];
#pragma unroll
    for (int i = 1; i < 4; i++) dB[tid + 256 * (i - 1)] = src[tid + 256 * i];
}

extern "C" void kernel_launch(void* const* d_in, const int* in_sizes, int n_in,
                              void* d_out, int out_size, void* d_ws, size_t ws_size,
                              hipStream_t stream) {
    const float* f1 = (const float*)d_in[0];
    const float* f2 = (const float*)d_in[1];
    float* out = (float*)d_out;

    hipLaunchKernelGGL(cg_gen, dim3(9), dim3(256), 0, stream);
    hipLaunchKernelGGL(etp_main, dim3(NROW), dim3(256), 0, stream,
                       f1, f2, out);
}

// Round 6
// 396.212 us; speedup vs baseline: 1.0896x; 1.0896x over previous
//
#include <hip/hip_runtime.h>
#include <cmath>

// ---------------------------------------------------------------------------
// Elementwise tensor product (e3nn-style), MUL=128, Ls=[0,1,2]
//   in : f1, f2  [16384, 1152] fp32
//   out:         [16384, 4480] fp32
// Round 6: CG table built on HOST (identical fp64 math), memcpyAsync'd to a
// device symbol (removes cg_gen kernel). Rebalanced half-block split
// (A=367 FMA: l0,l1,(2,0),(2,4); B=400 FMA: (2,1),(2,2),(2,3)).
// Direct strided input loads, LDS output stage, coalesced copy-out.
// ---------------------------------------------------------------------------

#define NROW 16384
#define DIN  1152
#define DOUT 4480

// table layout (floats): (l,lo) -> offset
//  (0,0):0[1] (1,0):1[9] (1,1):10[27] (1,2):37[45]
//  (2,0):82[25] (2,1):107[75] (2,2):182[125] (2,3):307[175] (2,4):482[225]  total 707
__device__ float g_cgtab[707];

// ======================= host-side CG table build ==========================
namespace cghost {

struct cd { double x, y; };
static inline cd cmul(cd a, cd b) {
    return cd{a.x * b.x - a.y * b.y, a.x * b.y + a.y * b.x};
}
static inline int imax(int a, int b) { return a > b ? a : b; }
static inline int imin(int a, int b) { return a < b ? a : b; }

static double fct[12];

static double su2_cg(int j1, int m1, int j2, int m2, int j3, int m3) {
    if (m3 != m1 + m2) return 0.0;
    const double* f = fct;
    int vmin = imax(imax(-j1 + j2 + m3, -j1 + m1), 0);
    int vmax = imin(imin(j2 + j3 + m1, j3 - j1 + j2), j3 + m3);
    if (vmax < vmin) return 0.0;
    double c = std::sqrt((2.0 * j3 + 1.0) *
                         f[j3 + j1 - j2] * f[j3 - j1 + j2] * f[j1 + j2 - j3] *
                         f[j3 + m3] * f[j3 - m3] /
                         (f[j1 + j2 + j3 + 1] * f[j1 - m1] * f[j1 + m1] *
                          f[j2 - m2] * f[j2 + m2]));
    double s = 0.0;
    for (int v = vmin; v <= vmax; ++v) {
        double num = f[j2 + j3 + m1 - v] * f[j1 - m1 + v];
        double den = f[v] * f[j3 - j1 + j2 - v] * f[j3 + m3 - v] * f[v + j1 - j2 - m3];
        double term = num / den;
        s += ((v + j2 + m2) & 1) ? -term : term;
    }
    return c * s;
}

// real->complex SH change of basis, e3nn convention incl (-i)^l phase
static void fill_cb(int l, cd* q) {
    int d = 2 * l + 1;
    for (int i = 0; i < d * d; i++) q[i] = cd{0.0, 0.0};
    const double is2 = 0.70710678118654752440;
    for (int m = -l; m < 0; m++) {
        q[(l + m) * d + (l - m)] = cd{is2, 0.0};
        q[(l + m) * d + (l + m)] = cd{0.0, -is2};
    }
    q[l * d + l] = cd{1.0, 0.0};
    for (int m = 1; m <= l; m++) {
        double sg = (m & 1) ? -1.0 : 1.0;
        q[(l + m) * d + (l + m)] = cd{sg * is2, 0.0};
        q[(l + m) * d + (l - m)] = cd{0.0, sg * is2};
    }
    int ph = l & 3;  // multiply by (-i)^l
    for (int i = 0; i < d * d; i++) {
        cd z = q[i], r;
        if (ph == 0) r = z;
        else if (ph == 1) r = cd{z.y, -z.x};
        else if (ph == 2) r = cd{-z.x, -z.y};
        else r = cd{-z.y, z.x};
        q[i] = r;
    }
}

// Build all 9 (l,lo) blocks into tab[707]; mirrors the validated device cg_gen.
static void build(float* tab) {
    fct[0] = 1.0;
    for (int i = 1; i < 12; i++) fct[i] = fct[i - 1] * i;

    for (int b = 0; b < 9; b++) {
        int l = (b == 0) ? 0 : (b < 4 ? 1 : 2);
        int lo = (b == 0) ? 0 : (b < 4 ? b - 1 : b - 4);
        int base = (l == 0) ? 0 : (l == 1 ? 1 : 82);
        int d2 = 2 * l + 1, d1 = 2 * lo + 1;
        int off = base + d2 * d2 * lo * lo;
        int Nent = d1 * d2 * d2;

        double su2[225];
        cd cb1[81], cb2[25];
        double val[225];

        for (int e = 0; e < Nent; e++) {
            int i = e / (d2 * d2), r = e % (d2 * d2);
            int k = r / d2, n = r % d2;
            su2[e] = su2_cg(lo, i - lo, l, k - l, l, n - l);
        }
        fill_cb(lo, cb1);
        fill_cb(l, cb2);

        // out[jo,kb,mb] = Re sum_{i,k,n} cb1[i,jo] cb2[k,kb] conj(cb2[n,mb]) su2[i,k,n]
        for (int e = 0; e < Nent; e++) {
            int jo = e / (d2 * d2), r = e % (d2 * d2);
            int kb = r / d2, mb = r % d2;
            double sx = 0.0;
            for (int i = 0; i < d1; i++) {
                cd c1 = cb1[i * d1 + jo];
                for (int k = 0; k < d2; k++) {
                    cd c12 = cmul(c1, cb2[k * d2 + kb]);
                    for (int n = 0; n < d2; n++) {
                        double cv = su2[(i * d2 + k) * d2 + n];
                        if (cv != 0.0) {
                            cd c3 = cb2[n * d2 + mb];
                            c3.y = -c3.y;  // conj
                            cd term = cmul(c12, c3);
                            sx += term.x * cv;
                        }
                    }
                }
            }
            val[e] = sx;
        }

        double ss = 0.0;
        for (int e = 0; e < Nent; e++) ss += val[e] * val[e];
        double scale = std::sqrt((double)d1) / std::sqrt(ss);
        for (int e = 0; e < Nent; e++) tab[off + e] = (float)(val[e] * scale);
    }
}

}  // namespace cghost

// Persistent host buffer: graph replay re-reads this address, so it must
// outlive kernel_launch. Rebuilt (same values) on every call — no call-count
// guards, idempotent.
static float h_cgtab[707];

// ============================ main kernel ==================================
// LDS out-stage layout per row (floats), 4096 total (16 KB):
//   (1,1)@0[384] (1,2)@384[640] (2,1)@1024[384] (2,2)@1408[640]
//   (2,3)@2048[896] (2,4)@2944[1152]
// out runs: lds[0..1024) -> out[256..1280); lds[1024..4096) -> out[1408..4480)

// os[k] = sum_e t[k*NE+e] * q[e]   (q = precomputed a_i*b_j products)
template <int DO_, int NE>
__device__ __forceinline__ void contractP(const float* __restrict__ t,
                                          const float* q,
                                          float* __restrict__ os) {
#pragma unroll
    for (int k = 0; k < DO_; k++) {
        float acc = 0.0f;
#pragma unroll
        for (int e = 0; e < NE; e++) acc = fmaf(t[k * NE + e], q[e], acc);
        os[k] = acc;
    }
}

__global__ __launch_bounds__(256, 6) void etp_main(
    const float* __restrict__ f1, const float* __restrict__ f2,
    float* __restrict__ out) {
    __shared__ alignas(16) float os[4096];
    const float* __restrict__ t = g_cgtab;  // uniform -> scalar loads

    const int tid = threadIdx.x;
    const int ch = tid & 127;
    const size_t row = blockIdx.x;

    const float* __restrict__ p1 = f1 + row * DIN;
    const float* __restrict__ p2 = f2 + row * DIN;
    float* __restrict__ po = out + row * DOUT;

    // ---- l=2 inputs + products: needed by both halves ----
    float a2[5], b2[5];
#pragma unroll
    for (int k = 0; k < 5; k++) {
        a2[k] = p1[512 + ch * 5 + k];
        b2[k] = p2[512 + ch * 5 + k];
    }
    float q2[25];
#pragma unroll
    for (int i = 0; i < 5; i++)
#pragma unroll
        for (int j = 0; j < 5; j++) q2[i * 5 + j] = a2[i] * b2[j];

    if (tid < 128) {
        // ---- half A (367 FMA): l=0, l=1 all, (2,0), (2,4) ----
        float a0 = p1[ch], b0 = p2[ch];
        po[ch] = t[0] * a0 * b0;  // (0,0)

        float a1[3], b1[3];
#pragma unroll
        for (int k = 0; k < 3; k++) {
            a1[k] = p1[128 + ch * 3 + k];
            b1[k] = p2[128 + ch * 3 + k];
        }
        float q1[9];
#pragma unroll
        for (int i = 0; i < 3; i++)
#pragma unroll
            for (int j = 0; j < 3; j++) q1[i * 3 + j] = a1[i] * b1[j];
        {
            float s = 0.0f;  // (1,0) direct
#pragma unroll
            for (int e = 0; e < 9; e++) s = fmaf(t[1 + e], q1[e], s);
            po[128 + ch] = s;
        }
        contractP<3, 9>(t + 10, q1, os + 0 + ch * 3);    // (1,1)
        contractP<5, 9>(t + 37, q1, os + 384 + ch * 5);  // (1,2)
        {
            float s = 0.0f;  // (2,0) direct
#pragma unroll
            for (int e = 0; e < 25; e++) s = fmaf(t[82 + e], q2[e], s);
            po[1280 + ch] = s;
        }
        contractP<9, 25>(t + 482, q2, os + 2944 + ch * 9);  // (2,4)
    } else {
        // ---- half B (400 FMA): (2,1), (2,2), (2,3) ----
        contractP<3, 25>(t + 107, q2, os + 1024 + ch * 3);  // (2,1)
        contractP<5, 25>(t + 182, q2, os + 1408 + ch * 5);  // (2,2)
        contractP<7, 25>(t + 307, q2, os + 2048 + ch * 7);  // (2,3)
    }

    __syncthreads();

    // ---- coalesced copy-out: 1024 float4 by 256 threads ----
    const float4* __restrict__ src = reinterpret_cast<const float4*>(os);
    float4* __restrict__ dA = reinterpret_cast<float4*>(po + 256);
    float4* __restrict__ dB = reinterpret_cast<float4*>(po + 1408);
    dA[tid] = src[tid];
#pragma unroll
    for (int i = 1; i < 4; i++) dB[tid + 256 * (i - 1)] = src[tid + 256 * i];
}

extern "C" void kernel_launch(void* const* d_in, const int* in_sizes, int n_in,
                              void* d_out, int out_size, void* d_ws, size_t ws_size,
                              hipStream_t stream) {
    const float* f1 = (const float*)d_in[0];
    const float* f2 = (const float*)d_in[1];
    float* out = (float*)d_out;

    // Rebuild the (constant) table every call — idempotent, no guards.
    cghost::build(h_cgtab);
    void* d_tab = nullptr;
    hipGetSymbolAddress(&d_tab, HIP_SYMBOL(g_cgtab));
    hipMemcpyAsync(d_tab, h_cgtab, sizeof(h_cgtab), hipMemcpyHostToDevice,
                   stream);

    hipLaunchKernelGGL(etp_main, dim3(NROW), dim3(256), 0, stream,
                       f1, f2, out);
}